// Round 7
// baseline (2767.835 us; speedup 1.0000x reference)
//
#include <hip/hip_runtime.h>

// Problem: B=128, T=512, I=512, H=2048, O=512, steps = T-2 = 510.
// Persistent-RNN, R13: OCCUPANCY. R10/R11/R12 proved the sync path is not
// the lever: dur stuck at ~2070us with MfmaUtil 14% / VALUBusy 18% / 67%
// idle at OccupancyPercent 12% = 1 wave/SIMD (82KB LDS -> 1 block/CU of 4
// waves; wf[16][4]+wih = >256 regs -> 1 wave/SIMD). One wave per SIMD means
// ZERO latency hiding -- every DMA/LDS/global latency is fully exposed,
// which is why shaving individual latencies was always neutral.
//   Change: k split 8 ways (was 4). 256 blocks x 512 threads (8 waves),
//   each wave owns a k-eighth: wf[8][4]=128 regs, wih[2][4]=32 -> ~230
//   regs/wave, __launch_bounds__(512,2) => 2 waves/SIMD. LDS 96KB (64 h +
//   32 red), still 1 block/CU. Two waves per SIMD overlap each other's
//   DMA-wait/LDS-read/MFMA-issue phases.
//   Sync semantics FROZEN from R6/R10: barrier #1 + barrier #2, single
//   relaxed agent flag store by tid 0, relaxed agent ballot poll (4
//   producers/wave now), per-chunk vmcnt DMA gating, dual L2/L3 h exchange.
#define Bsz 128
#define Tsz 512
#define Isz 512
#define Hsz 2048
#define Osz 512
#define STEPS 510

typedef short short8 __attribute__((ext_vector_type(8)));
typedef float floatx4 __attribute__((ext_vector_type(4)));

// fp32 -> bf16 round-to-nearest-even (finite inputs only)
__device__ __forceinline__ unsigned short f2bf(float f) {
  unsigned int u = __builtin_bit_cast(unsigned int, f);
  u += 0x7FFFu + ((u >> 16) & 1u);
  return (unsigned short)(u >> 16);
}

// exact identity tanh(x) = 1 - 2/(e^{2x}+1); exp+rcp ~1ulp, abs err ~1e-7
__device__ __forceinline__ float tanh_fast(float x) {
  const float e = __expf(2.f * x);
  return 1.f - 2.f * __builtin_amdgcn_rcpf(e + 1.f);
}

// async global->LDS, 16B/lane; global src per-lane (ptr + lane*16B), LDS dest
// wave-uniform base. AUX CPol: 0x11 = SC0|SC1 (device-coherent, read L3),
// 0x01 = SC0 (bypass L1 only; read shared XCD L2 -- hits producer-dirty lines)
template <int AUX>
__device__ __forceinline__ void gload_lds16(const void* g, void* l) {
  __builtin_amdgcn_global_load_lds(
      (const __attribute__((address_space(1))) void*)g,
      (__attribute__((address_space(3))) void*)l, 16, 0, AUX);
}

// h-chunk compute: wait for chunk c's two DMAs (8 issued; issue-order
// retirement => chunk c complete at vmcnt(6-2c)), then 2 LDS vector reads +
// 8 MFMAs. enc = 0x0F70 | (6-2c).
#define HCHUNK(c, enc)                                                                         \
  {                                                                                            \
    __builtin_amdgcn_s_waitcnt(enc);                                                           \
    const int hb = wvoff + (c) * 1024 + m16 * 64;                                              \
    const short8 a0 = *reinterpret_cast<const short8*>(&h_lds[hb + (quad ^ m7) * 8]);          \
    acc[0] = __builtin_amdgcn_mfma_f32_16x16x32_bf16(a0, wf[(c) * 2][0], acc[0], 0, 0, 0);     \
    acc[1] = __builtin_amdgcn_mfma_f32_16x16x32_bf16(a0, wf[(c) * 2][1], acc[1], 0, 0, 0);     \
    acc[2] = __builtin_amdgcn_mfma_f32_16x16x32_bf16(a0, wf[(c) * 2][2], acc[2], 0, 0, 0);     \
    acc[3] = __builtin_amdgcn_mfma_f32_16x16x32_bf16(a0, wf[(c) * 2][3], acc[3], 0, 0, 0);     \
    const short8 a1 = *reinterpret_cast<const short8*>(&h_lds[hb + ((4 + quad) ^ m7) * 8]);    \
    acc[0] = __builtin_amdgcn_mfma_f32_16x16x32_bf16(a1, wf[(c) * 2 + 1][0], acc[0], 0, 0, 0); \
    acc[1] = __builtin_amdgcn_mfma_f32_16x16x32_bf16(a1, wf[(c) * 2 + 1][1], acc[1], 0, 0, 0); \
    acc[2] = __builtin_amdgcn_mfma_f32_16x16x32_bf16(a1, wf[(c) * 2 + 1][2], acc[2], 0, 0, 0); \
    acc[3] = __builtin_amdgcn_mfma_f32_16x16x32_bf16(a1, wf[(c) * 2 + 1][3], acc[3], 0, 0, 0); \
  }

__global__ __launch_bounds__(512, 2)
void rnn_kernel(const float* __restrict__ x, const float* __restrict__ h0v,
                const float* __restrict__ W_ih, const float* __restrict__ b_ih,
                const float* __restrict__ W_hh, const float* __restrict__ b_hh,
                unsigned short* __restrict__ hbuf,  // [2][32 cg][8 rg][1024] swizzled bf16 tiles
                float* __restrict__ hfinal,         // [128][2048] f32
                unsigned int* __restrict__ flags,   // [32 cg][8 rg] step counters
                unsigned int* __restrict__ xcc_arr) // [8 rg][32 cg] XCC id + 1
{
  __shared__ short h_lds[8 * 4096];   // 64 KB: per-wave 4 chunk-tiles [16][64], swizzled
  __shared__ float red_lds[8 * 1024]; // 32 KB: 8 k-split partials
  __shared__ int pad_lds[16];
  __shared__ unsigned int mode_lds;   // 1 = same-XCD L2 exchange legal

  const int tid = threadIdx.x;
  const int lane = tid & 63;
  const int wv = tid >> 6;    // wave 0..7 -> k-eighth
  const int m16 = lane & 15;  // MFMA: A row / B col / C col
  const int quad = lane >> 4;
  const int m7 = m16 & 7;
  const int rg = blockIdx.x & 7;   // row group (bid%8 -> XCD under round-robin)
  const int cg = blockIdx.x >> 3;  // col group 0..31
  const int b0 = rg * 16;
  const int c0 = cg * 64;
  const int kq = wv * 256;   // W_hh k-range for this wave
  const int kqx = wv * 64;   // W_ih k-range
  const int wvoff = wv * 4096;  // this wave's h_lds region (shorts)

  // ---- runtime XCD-colocation check (publish + verify all 32 rg members) ----
  {
    unsigned int xcc;
    asm volatile("s_getreg_b32 %0, hwreg(HW_REG_XCC_ID)" : "=s"(xcc));
    if (tid == 0)
      __hip_atomic_store(&xcc_arr[rg * 32 + cg], xcc + 1u, __ATOMIC_RELAXED,
                         __HIP_MEMORY_SCOPE_AGENT);
    if (wv == 0) {
      const unsigned int* ap = &xcc_arr[rg * 32 + (lane & 31)];
      unsigned int v;
      do {
        v = __hip_atomic_load(ap, __ATOMIC_RELAXED, __HIP_MEMORY_SCOPE_AGENT);
        if (__all((int)(v != 0u))) break;
        __builtin_amdgcn_s_sleep(2);
      } while (true);
      const int same = __all((int)(v == xcc + 1u));
      if (tid == 0) mode_lds = (unsigned int)same;
    }
  }

  // ---- one-time: weight slices -> bf16 B-fragments in registers ----
  // B-frag: lane holds B[k = quad*8 + j][n = lane&15]
  short8 wf[8][4];   // [kchunk within eighth][ntile]  = 128 VGPR
  short8 wih[2][4];  // 32 VGPR
#pragma unroll
  for (int nt = 0; nt < 4; ++nt) {
    const int wrow = c0 + nt * 16 + m16;  // W row = output col j
    const float* base = W_hh + (size_t)wrow * Hsz + kq + quad * 8;
#pragma unroll
    for (int kc = 0; kc < 8; ++kc) {
      short8 v;
#pragma unroll
      for (int j = 0; j < 8; ++j) v[j] = (short)f2bf(base[kc * 32 + j]);
      wf[kc][nt] = v;
    }
    const float* basex = W_ih + (size_t)wrow * Isz + kqx + quad * 8;
#pragma unroll
    for (int kc = 0; kc < 2; ++kc) {
      short8 v;
#pragma unroll
      for (int j = 0; j < 8; ++j) v[j] = (short)f2bf(basex[kc * 32 + j]);
      wih[kc][nt] = v;
    }
  }

  // reduce-phase assignment: thread handles (row=tid>>5, 2 cols at 2*(tid&31))
  const int rrow = tid >> 5;
  const int cb = (tid & 31) * 2;
  const float bias0 = b_ih[c0 + cb] + b_hh[c0 + cb];
  const float bias1 = b_ih[c0 + cb + 1] + b_hh[c0 + cb + 1];

  if (tid < 16)
    pad_lds[tid] = (int)x[(size_t)(b0 + tid) * (Tsz * Isz) + (size_t)(Tsz - 1) * Isz];

  // h_0 = h0 broadcast into this wave's 4 tiles (swizzled layout)
  for (int i = lane; i < 512; i += 64) {  // i = 16B-unit index in wave region
    const int c = i >> 7;          // tile 0..3
    const int r = (i >> 3) & 15;   // row 0..15
    const int u = i & 7;           // unit 0..7
    const int k = kq + c * 64 + u * 8;
    short8 v;
#pragma unroll
    for (int j = 0; j < 8; ++j) v[j] = (short)f2bf(h0v[k + j]);
    *reinterpret_cast<short8*>(&h_lds[wvoff + c * 1024 + r * 64 + (u ^ (r & 7)) * 8]) = v;
  }

  __syncthreads();  // mode_lds + pad_lds visible to all waves
  const bool use_l2 = (mode_lds != 0u);

  // this wave's poll address: lane L watches producer cg' = wv*4 + (L&3)
  const unsigned int* fp = flags + (size_t)(wv * 4 + (lane & 3)) * 8 + rg;

  for (int t = 0; t < STEPS; ++t) {
    const bool have_next = (t + 1) < STEPS;

    // x for this step: direct global->VGPR (drained by the poll's wait)
    const float* xp = x + (size_t)(b0 + m16) * (Tsz * Isz) + (size_t)t * Isz + kqx + quad * 8;
    float4 xv[4];
#pragma unroll
    for (int kcc = 0; kcc < 2; ++kcc) {
      xv[2 * kcc] = *reinterpret_cast<const float4*>(xp + kcc * 32);
      xv[2 * kcc + 1] = *reinterpret_cast<const float4*>(xp + kcc * 32 + 4);
    }

    if (t > 0) {
      // ONE ballot poll: all lanes load the wave's 4 producer flags
      while (!__all((int)(__hip_atomic_load(fp, __ATOMIC_RELAXED,
                                            __HIP_MEMORY_SCOPE_AGENT) >= (unsigned)t)))
        __builtin_amdgcn_s_sleep(1);
      // issue all 8 chunk DMAs back-to-back (no intervening waits)
      const unsigned short* hsrcp = hbuf + (size_t)(t & 1) * (Bsz * Hsz);
      if (use_l2) {
#pragma unroll
        for (int c = 0; c < 4; ++c) {
          const unsigned short* src = hsrcp + (size_t)((wv * 4 + c) * 8 + rg) * 1024;
          gload_lds16<0x01>(src + lane * 8, &h_lds[wvoff + c * 1024]);
          gload_lds16<0x01>(src + 512 + lane * 8, &h_lds[wvoff + c * 1024 + 512]);
        }
      } else {
#pragma unroll
        for (int c = 0; c < 4; ++c) {
          const unsigned short* src = hsrcp + (size_t)((wv * 4 + c) * 8 + rg) * 1024;
          gload_lds16<0x11>(src + lane * 8, &h_lds[wvoff + c * 1024]);
          gload_lds16<0x11>(src + 512 + lane * 8, &h_lds[wvoff + c * 1024 + 512]);
        }
      }
    }

    // convert x to A-frags (xv already complete: drained by poll's first wait)
    short8 xa[2];
#pragma unroll
    for (int kcc = 0; kcc < 2; ++kcc) {
      short8 a;
      a[0] = (short)f2bf(xv[2 * kcc].x);
      a[1] = (short)f2bf(xv[2 * kcc].y);
      a[2] = (short)f2bf(xv[2 * kcc].z);
      a[3] = (short)f2bf(xv[2 * kcc].w);
      a[4] = (short)f2bf(xv[2 * kcc + 1].x);
      a[5] = (short)f2bf(xv[2 * kcc + 1].y);
      a[6] = (short)f2bf(xv[2 * kcc + 1].z);
      a[7] = (short)f2bf(xv[2 * kcc + 1].w);
      xa[kcc] = a;
    }

    floatx4 acc[4];
#pragma unroll
    for (int nt = 0; nt < 4; ++nt) {
      floatx4 zero = {0.f, 0.f, 0.f, 0.f};
      acc[nt] = zero;
    }
    // x-projection MFMAs (overlap DMA flight)
#pragma unroll
    for (int kcc = 0; kcc < 2; ++kcc)
#pragma unroll
      for (int nt = 0; nt < 4; ++nt)
        acc[nt] = __builtin_amdgcn_mfma_f32_16x16x32_bf16(xa[kcc], wih[kcc][nt], acc[nt], 0, 0, 0);

    // per-chunk gated h-MFMAs: chunk c ready at vmcnt(6-2c) (issue-order).
    // At t=0 no DMAs outstanding; waits pass trivially (h_lds holds h_0).
    HCHUNK(0, 0x0F76)
    HCHUNK(1, 0x0F74)
    HCHUNK(2, 0x0F72)
    HCHUNK(3, 0x0F70)

    // partials -> LDS (C layout: row = quad*4+reg, col = nt*16 + lane&15)
#pragma unroll
    for (int nt = 0; nt < 4; ++nt)
#pragma unroll
      for (int i = 0; i < 4; ++i)
        red_lds[wv * 1024 + (quad * 4 + i) * 64 + nt * 16 + m16] = acc[nt][i];

    __syncthreads();  // barrier #1: partials visible to reduce threads

    // ---- reduce 8 k-partials + bias, tanh, store h_{t+1} tile, capture pad ----
    {
      float z0 = 0.f, z1 = 0.f;
#pragma unroll
      for (int ww = 0; ww < 8; ++ww) {
        const float2 p =
            *reinterpret_cast<const float2*>(&red_lds[ww * 1024 + rrow * 64 + cb]);
        z0 += p.x; z1 += p.y;
      }
      const float t0 = tanh_fast(z0 + bias0);
      const float t1 = tanh_fast(z1 + bias1);
      const unsigned int pk =
          (unsigned int)f2bf(t0) | ((unsigned int)f2bf(t1) << 16);
      // swizzled tile store: unit (cb/8) ^ (row&7), short pos cb&7 (even)
      const int toff = rrow * 64 + ((cb >> 3) ^ (rrow & 7)) * 8 + (cb & 7);
      unsigned short* hd = hbuf + (size_t)((t + 1) & 1) * (Bsz * Hsz) +
                           (size_t)(cg * 8 + rg) * 1024 + toff;
      if (use_l2) {
        // plain write-back store: dirty in the SHARED XCD L2 (coherent for
        // same-L2 readers; eviction goes to L3 which SC0 readers then fill from)
        *reinterpret_cast<unsigned int*>(hd) = pk;
      } else {
        // device-coherent store: write-through to L3 (the coherence point)
        __hip_atomic_store(reinterpret_cast<unsigned int*>(hd), pk,
                           __ATOMIC_RELAXED, __HIP_MEMORY_SCOPE_AGENT);
      }
      if (pad_lds[rrow] == t) {
        float2 o;
        o.x = t0; o.y = t1;
        *reinterpret_cast<float2*>(&hfinal[(size_t)(b0 + rrow) * Hsz + c0 + cb]) = o;
      }
    }

    __syncthreads();  // barrier #2: full vmcnt drain -> h committed before post

    if (have_next && tid == 0) {
      // single-writer flag: plain relaxed coherent store, no RMW, no fence
      __hip_atomic_store(flags + cg * 8 + rg, (unsigned)(t + 1),
                         __ATOMIC_RELAXED, __HIP_MEMORY_SCOPE_AGENT);
    }
  }
}

// out[b][o] = hfinal[b][:] . W_fc[o][:] + b_fc[o]; 8 b-tiles x 32 o-tiles
__global__ __launch_bounds__(64)
void fc_kernel(const float* __restrict__ hfinal, const float* __restrict__ W_fc,
               const float* __restrict__ b_fc, float* __restrict__ out) {
  const int lane = threadIdx.x & 63;
  const int m16 = lane & 15;
  const int quad = lane >> 4;
  const int b0 = (blockIdx.x & 7) * 16;
  const int o0 = (blockIdx.x >> 3) * 16;
  floatx4 acc = {0.f, 0.f, 0.f, 0.f};
  const float* ap = hfinal + (size_t)(b0 + m16) * Hsz + quad * 8;
  const float* bp = W_fc + (size_t)(o0 + m16) * Hsz + quad * 8;
#pragma unroll 4
  for (int kc = 0; kc < 64; ++kc) {
    short8 a, b;
#pragma unroll
    for (int j = 0; j < 8; ++j) a[j] = (short)f2bf(ap[kc * 32 + j]);
#pragma unroll
    for (int j = 0; j < 8; ++j) b[j] = (short)f2bf(bp[kc * 32 + j]);
    acc = __builtin_amdgcn_mfma_f32_16x16x32_bf16(a, b, acc, 0, 0, 0);
  }
  const float bias = b_fc[o0 + m16];
#pragma unroll
  for (int i = 0; i < 4; ++i)
    out[(size_t)(b0 + quad * 4 + i) * Osz + o0 + m16] = acc[i] + bias;
}

__global__ void zero_flags(unsigned int* f) { f[blockIdx.x * 256 + threadIdx.x] = 0u; }

extern "C" void kernel_launch(void* const* d_in, const int* in_sizes, int n_in,
                              void* d_out, int out_size, void* d_ws, size_t ws_size,
                              hipStream_t stream) {
  const float* x = (const float*)d_in[0];
  const float* h0 = (const float*)d_in[1];
  const float* W_ih = (const float*)d_in[2];
  const float* b_ih = (const float*)d_in[3];
  const float* W_hh = (const float*)d_in[4];
  const float* b_hh = (const float*)d_in[5];
  const float* W_fc = (const float*)d_in[6];
  const float* b_fc = (const float*)d_in[7];
  float* out = (float*)d_out;

  char* ws = (char*)d_ws;
  unsigned short* hbuf = (unsigned short*)ws;              // 1 MiB (2x 512KB tile slabs)
  float* hfinal = (float*)(ws + (1u << 20));               // 1 MiB
  unsigned int* flags = (unsigned int*)(ws + (2u << 20));  // 1 KiB flags
  unsigned int* xcc_arr = flags + 256;                     // 1 KiB xcc ids

  zero_flags<<<2, 256, 0, stream>>>(flags);  // zero flags + xcc_arr
  rnn_kernel<<<256, 512, 0, stream>>>(x, h0, W_ih, b_ih, W_hh, b_hh, hbuf, hfinal,
                                      flags, xcc_arr);
  fc_kernel<<<256, 64, 0, stream>>>(hfinal, W_fc, b_fc, out);
}

// Round 8
// 2101.398 us; speedup vs baseline: 1.3171x; 1.3171x over previous
//
#include <hip/hip_runtime.h>

// Problem: B=128, T=512, I=512, H=2048, O=512, steps = T-2 = 510.
// Persistent-RNN, R14: GUARANTEE the h-exchange is intra-XCD (L2-served).
//   R10-R13 falsified: DMA exposure, poll contention, barrier rendezvous,
//   post latency, occupancy. Remaining unverified component: whether the
//   use_l2 fast path (SC0 DMA + plain write-back h stores, intra-XCD L2)
//   ever actually engaged. It requires dispatch to place all 32 blocks of a
//   rg on one XCD under bid%8 -- never verified, and if false the exchange
//   runs through L3: 16MB/step chip-wide ~3300cy BW-bound + fabric jitter,
//   matching the observed 9750cy step.
//   Change: blocks claim their (rg,cg) identity FROM their measured XCD:
//   per-XCD atomic ticket; first 32 claimants of XCD k become (rg=k,cg=slot).
//   Uneven-dispatch overflow blocks CAS-scan leftover slots after a
//   done-rendezvous (deadlock-free; bijection guaranteed). Clean groups are
//   same-XCD by construction -> existing verification enables use_l2.
//   All R6/R10 sync semantics FROZEN (relaxed agent flags/poll, 2 barriers,
//   per-chunk vmcnt DMA gating). Claim-store ordered before done-increment
//   by wave-level s_waitcnt vmcnt(0) (plain drain, NOT R9's release/wbl2).
#define Bsz 128
#define Tsz 512
#define Isz 512
#define Hsz 2048
#define Osz 512
#define STEPS 510

typedef short short8 __attribute__((ext_vector_type(8)));
typedef float floatx4 __attribute__((ext_vector_type(4)));

// fp32 -> bf16 round-to-nearest-even (finite inputs only)
__device__ __forceinline__ unsigned short f2bf(float f) {
  unsigned int u = __builtin_bit_cast(unsigned int, f);
  u += 0x7FFFu + ((u >> 16) & 1u);
  return (unsigned short)(u >> 16);
}

// exact identity tanh(x) = 1 - 2/(e^{2x}+1); exp+rcp ~1ulp, abs err ~1e-7
__device__ __forceinline__ float tanh_fast(float x) {
  const float e = __expf(2.f * x);
  return 1.f - 2.f * __builtin_amdgcn_rcpf(e + 1.f);
}

// async global->LDS, 16B/lane; global src per-lane (ptr + lane*16B), LDS dest
// wave-uniform base. AUX CPol: 0x11 = SC0|SC1 (device-coherent, read L3),
// 0x01 = SC0 (bypass L1 only; read shared XCD L2 -- hits producer-dirty lines)
template <int AUX>
__device__ __forceinline__ void gload_lds16(const void* g, void* l) {
  __builtin_amdgcn_global_load_lds(
      (const __attribute__((address_space(1))) void*)g,
      (__attribute__((address_space(3))) void*)l, 16, 0, AUX);
}

// h-chunk compute: wait for chunk c's two DMAs (issue-order retirement =>
// vmcnt(14-2c)), then 2 LDS vector reads + 8 MFMAs. enc = 0x0F70 | (14-2c).
#define HCHUNK(c, enc)                                                                         \
  {                                                                                            \
    __builtin_amdgcn_s_waitcnt(enc);                                                           \
    const int hb = wvoff + (c) * 1024 + m16 * 64;                                              \
    const short8 a0 = *reinterpret_cast<const short8*>(&h_lds[hb + (quad ^ m7) * 8]);          \
    acc[0] = __builtin_amdgcn_mfma_f32_16x16x32_bf16(a0, wf[(c) * 2][0], acc[0], 0, 0, 0);     \
    acc[1] = __builtin_amdgcn_mfma_f32_16x16x32_bf16(a0, wf[(c) * 2][1], acc[1], 0, 0, 0);     \
    acc[2] = __builtin_amdgcn_mfma_f32_16x16x32_bf16(a0, wf[(c) * 2][2], acc[2], 0, 0, 0);     \
    acc[3] = __builtin_amdgcn_mfma_f32_16x16x32_bf16(a0, wf[(c) * 2][3], acc[3], 0, 0, 0);     \
    const short8 a1 = *reinterpret_cast<const short8*>(&h_lds[hb + ((4 + quad) ^ m7) * 8]);    \
    acc[0] = __builtin_amdgcn_mfma_f32_16x16x32_bf16(a1, wf[(c) * 2 + 1][0], acc[0], 0, 0, 0); \
    acc[1] = __builtin_amdgcn_mfma_f32_16x16x32_bf16(a1, wf[(c) * 2 + 1][1], acc[1], 0, 0, 0); \
    acc[2] = __builtin_amdgcn_mfma_f32_16x16x32_bf16(a1, wf[(c) * 2 + 1][2], acc[2], 0, 0, 0); \
    acc[3] = __builtin_amdgcn_mfma_f32_16x16x32_bf16(a1, wf[(c) * 2 + 1][3], acc[3], 0, 0, 0); \
  }

__global__ __launch_bounds__(256, 1)
void rnn_kernel(const float* __restrict__ x, const float* __restrict__ h0v,
                const float* __restrict__ W_ih, const float* __restrict__ b_ih,
                const float* __restrict__ W_hh, const float* __restrict__ b_hh,
                unsigned short* __restrict__ hbuf,  // [2][32 cg][8 rg][1024] swizzled bf16 tiles
                float* __restrict__ hfinal,         // [128][2048] f32
                unsigned int* __restrict__ flags,   // [32 cg][8 rg] step counters
                unsigned int* __restrict__ xcc_arr, // [8 rg][32 cg] XCC id + 1
                unsigned int* __restrict__ claimed, // [8 rg][32 cg] slot claim map
                unsigned int* __restrict__ xcd_cnt, // [8] per-XCD tickets
                unsigned int* __restrict__ done_cnt)// [1] rendezvous counter
{
  __shared__ short h_lds[4 * 8192];   // 64 KB: per-wave 8 chunk-tiles [16][64], swizzled
  __shared__ float red_lds[4 * 1024]; // 16 KB: k-split partials
  __shared__ int pad_lds[16];
  __shared__ unsigned int mode_lds;   // 1 = same-XCD L2 exchange legal
  __shared__ int rgcg_lds;            // claimed identity (rg<<8 | cg)

  const int tid = threadIdx.x;
  const int lane = tid & 63;
  const int wv = tid >> 6;    // wave 0..3 -> k-quarter
  const int m16 = lane & 15;  // MFMA: A row / B col / C col
  const int quad = lane >> 4;
  const int m7 = m16 & 7;

  // ---- XCD-aware identity claim: (rg,cg) derived from MEASURED XCD ----
  unsigned int xcc;
  asm volatile("s_getreg_b32 %0, hwreg(HW_REG_XCC_ID)" : "=s"(xcc));
  xcc &= 7u;
  if (tid == 0) {
    const unsigned int slot = __hip_atomic_fetch_add(&xcd_cnt[xcc], 1u,
                                                     __ATOMIC_RELAXED,
                                                     __HIP_MEMORY_SCOPE_AGENT);
    int myrg, mycg;
    if (slot < 32u) {
      myrg = (int)xcc; mycg = (int)slot;
      __hip_atomic_store(&claimed[myrg * 32 + mycg], 1u, __ATOMIC_RELAXED,
                         __HIP_MEMORY_SCOPE_AGENT);
      // drain the claim store to the coherence point BEFORE the done add so
      // any block observing done==256 also observes this claim (plain wave
      // drain; relaxed ops only -- no wbl2)
      asm volatile("s_waitcnt vmcnt(0)" ::: "memory");
      __hip_atomic_fetch_add(done_cnt, 1u, __ATOMIC_RELAXED,
                             __HIP_MEMORY_SCOPE_AGENT);
    } else {
      __hip_atomic_fetch_add(done_cnt, 1u, __ATOMIC_RELAXED,
                             __HIP_MEMORY_SCOPE_AGENT);
      while (__hip_atomic_load(done_cnt, __ATOMIC_RELAXED,
                               __HIP_MEMORY_SCOPE_AGENT) < 256u)
        __builtin_amdgcn_s_sleep(2);
      myrg = -1; mycg = 0;
      for (int j = 0;; j = (j + 1) & 255) {
        if (__hip_atomic_load(&claimed[j], __ATOMIC_RELAXED,
                              __HIP_MEMORY_SCOPE_AGENT) == 0u) {
          unsigned int exp = 0u;
          if (__hip_atomic_compare_exchange_strong(
                  &claimed[j], &exp, 1u, __ATOMIC_RELAXED, __ATOMIC_RELAXED,
                  __HIP_MEMORY_SCOPE_AGENT)) {
            myrg = j >> 5; mycg = j & 31;
            break;
          }
        }
      }
    }
    rgcg_lds = (myrg << 8) | mycg;
  }
  __syncthreads();
  const int rg = rgcg_lds >> 8;   // row group (== this XCD for clean groups)
  const int cg = rgcg_lds & 255;  // col group 0..31
  const int b0 = rg * 16;
  const int c0 = cg * 64;
  const int kq = wv * 512;   // W_hh k-range for this wave
  const int kqx = wv * 128;  // W_ih k-range
  const int wvoff = wv * 8192;  // this wave's h_lds region (shorts)

  // ---- runtime XCD-colocation check (publish + verify all 32 rg members) ----
  {
    if (tid == 0)
      __hip_atomic_store(&xcc_arr[rg * 32 + cg], xcc + 1u, __ATOMIC_RELAXED,
                         __HIP_MEMORY_SCOPE_AGENT);
    if (wv == 0) {
      const unsigned int* ap = &xcc_arr[rg * 32 + (lane & 31)];
      unsigned int v;
      do {
        v = __hip_atomic_load(ap, __ATOMIC_RELAXED, __HIP_MEMORY_SCOPE_AGENT);
        if (__all((int)(v != 0u))) break;
        __builtin_amdgcn_s_sleep(2);
      } while (true);
      const int same = __all((int)(v == xcc + 1u));
      if (tid == 0) mode_lds = (unsigned int)same;
    }
  }

  // ---- one-time: weight slices -> bf16 B-fragments in registers ----
  // B-frag: lane holds B[k = quad*8 + j][n = lane&15]
  short8 wf[16][4];  // [kchunk within quarter][ntile]
  short8 wih[4][4];
#pragma unroll
  for (int nt = 0; nt < 4; ++nt) {
    const int wrow = c0 + nt * 16 + m16;  // W row = output col j
    const float* base = W_hh + (size_t)wrow * Hsz + kq + quad * 8;
#pragma unroll
    for (int kc = 0; kc < 16; ++kc) {
      short8 v;
#pragma unroll
      for (int j = 0; j < 8; ++j) v[j] = (short)f2bf(base[kc * 32 + j]);
      wf[kc][nt] = v;
    }
    const float* basex = W_ih + (size_t)wrow * Isz + kqx + quad * 8;
#pragma unroll
    for (int kc = 0; kc < 4; ++kc) {
      short8 v;
#pragma unroll
      for (int j = 0; j < 8; ++j) v[j] = (short)f2bf(basex[kc * 32 + j]);
      wih[kc][nt] = v;
    }
  }

  // reduce-phase assignment: thread handles (row=tid>>4, 4 cols at 4*(tid&15))
  const int rrow = tid >> 4;
  const int rcb = (tid & 15) * 4;
  float bias[4];
#pragma unroll
  for (int i = 0; i < 4; ++i) bias[i] = b_ih[c0 + rcb + i] + b_hh[c0 + rcb + i];

  if (tid < 16)
    pad_lds[tid] = (int)x[(size_t)(b0 + tid) * (Tsz * Isz) + (size_t)(Tsz - 1) * Isz];

  // h_0 = h0 broadcast into this wave's 8 tiles (swizzled layout)
  for (int i = lane; i < 1024; i += 64) {  // i = 16B-unit index in wave region
    const int c = i >> 7;          // tile 0..7
    const int r = (i >> 3) & 15;   // row 0..15
    const int u = i & 7;           // unit 0..7
    const int k = kq + c * 64 + u * 8;
    short8 v;
#pragma unroll
    for (int j = 0; j < 8; ++j) v[j] = (short)f2bf(h0v[k + j]);
    *reinterpret_cast<short8*>(&h_lds[wvoff + c * 1024 + r * 64 + (u ^ (r & 7)) * 8]) = v;
  }

  __syncthreads();  // mode_lds + pad_lds visible to all waves
  const bool use_l2 = (mode_lds != 0u);

  // this wave's poll address: lane L watches producer cg = wv*8 + (L&7)
  const unsigned int* fp = flags + (size_t)(wv * 8 + (lane & 7)) * 8 + rg;

  for (int t = 0; t < STEPS; ++t) {
    const bool have_next = (t + 1) < STEPS;

    // x for this step: direct global->VGPR (drained once by the poll's wait)
    const float* xp = x + (size_t)(b0 + m16) * (Tsz * Isz) + (size_t)t * Isz + kqx + quad * 8;
    float4 xv[8];
#pragma unroll
    for (int kcc = 0; kcc < 4; ++kcc) {
      xv[2 * kcc] = *reinterpret_cast<const float4*>(xp + kcc * 32);
      xv[2 * kcc + 1] = *reinterpret_cast<const float4*>(xp + kcc * 32 + 4);
    }

    if (t > 0) {
      // ONE ballot poll: all 64 lanes load the wave's 8 producer flags
      while (!__all((int)(__hip_atomic_load(fp, __ATOMIC_RELAXED,
                                            __HIP_MEMORY_SCOPE_AGENT) >= (unsigned)t)))
        __builtin_amdgcn_s_sleep(1);
      // issue all 16 chunk DMAs back-to-back (no intervening waits)
      const unsigned short* hsrcp = hbuf + (size_t)(t & 1) * (Bsz * Hsz);
      if (use_l2) {
#pragma unroll
        for (int c = 0; c < 8; ++c) {
          const unsigned short* src = hsrcp + (size_t)((wv * 8 + c) * 8 + rg) * 1024;
          gload_lds16<0x01>(src + lane * 8, &h_lds[wvoff + c * 1024]);
          gload_lds16<0x01>(src + 512 + lane * 8, &h_lds[wvoff + c * 1024 + 512]);
        }
      } else {
#pragma unroll
        for (int c = 0; c < 8; ++c) {
          const unsigned short* src = hsrcp + (size_t)((wv * 8 + c) * 8 + rg) * 1024;
          gload_lds16<0x11>(src + lane * 8, &h_lds[wvoff + c * 1024]);
          gload_lds16<0x11>(src + 512 + lane * 8, &h_lds[wvoff + c * 1024 + 512]);
        }
      }
    }

    // convert x to A-frags (xv already complete: drained by poll's first wait)
    short8 xa[4];
#pragma unroll
    for (int kcc = 0; kcc < 4; ++kcc) {
      short8 a;
      a[0] = (short)f2bf(xv[2 * kcc].x);
      a[1] = (short)f2bf(xv[2 * kcc].y);
      a[2] = (short)f2bf(xv[2 * kcc].z);
      a[3] = (short)f2bf(xv[2 * kcc].w);
      a[4] = (short)f2bf(xv[2 * kcc + 1].x);
      a[5] = (short)f2bf(xv[2 * kcc + 1].y);
      a[6] = (short)f2bf(xv[2 * kcc + 1].z);
      a[7] = (short)f2bf(xv[2 * kcc + 1].w);
      xa[kcc] = a;
    }

    floatx4 acc[4];
#pragma unroll
    for (int nt = 0; nt < 4; ++nt) {
      floatx4 zero = {0.f, 0.f, 0.f, 0.f};
      acc[nt] = zero;
    }
    // x-projection MFMAs (overlap DMA flight)
#pragma unroll
    for (int kcc = 0; kcc < 4; ++kcc)
#pragma unroll
      for (int nt = 0; nt < 4; ++nt)
        acc[nt] = __builtin_amdgcn_mfma_f32_16x16x32_bf16(xa[kcc], wih[kcc][nt], acc[nt], 0, 0, 0);

    // per-chunk gated h-MFMAs: chunk c ready at vmcnt(14-2c) (issue-order).
    // At t=0 there are no DMAs outstanding; waits pass trivially and h_lds
    // holds the pre-filled h_0 tiles.
    HCHUNK(0, 0x0F7E)
    HCHUNK(1, 0x0F7C)
    HCHUNK(2, 0x0F7A)
    HCHUNK(3, 0x0F78)
    HCHUNK(4, 0x0F76)
    HCHUNK(5, 0x0F74)
    HCHUNK(6, 0x0F72)
    HCHUNK(7, 0x0F70)

    // partials -> LDS (C layout: row = quad*4+reg, col = nt*16 + lane&15)
#pragma unroll
    for (int nt = 0; nt < 4; ++nt)
#pragma unroll
      for (int i = 0; i < 4; ++i)
        red_lds[wv * 1024 + (quad * 4 + i) * 64 + nt * 16 + m16] = acc[nt][i];

    __syncthreads();  // barrier #1: partials visible to reduce threads

    // ---- reduce 4 k-partials + bias, tanh, store h_{t+1} tile, capture pad ----
    {
      float4 z = {0.f, 0.f, 0.f, 0.f};
#pragma unroll
      for (int ww = 0; ww < 4; ++ww) {
        const float4 p =
            *reinterpret_cast<const float4*>(&red_lds[ww * 1024 + rrow * 64 + rcb]);
        z.x += p.x; z.y += p.y; z.z += p.z; z.w += p.w;
      }
      const float t0 = tanh_fast(z.x + bias[0]);
      const float t1 = tanh_fast(z.y + bias[1]);
      const float t2 = tanh_fast(z.z + bias[2]);
      const float t3 = tanh_fast(z.w + bias[3]);
      unsigned long long pk = (unsigned long long)f2bf(t0) |
                              ((unsigned long long)f2bf(t1) << 16) |
                              ((unsigned long long)f2bf(t2) << 32) |
                              ((unsigned long long)f2bf(t3) << 48);
      // swizzled tile store: unit (rcb/8) ^ (row&7), half-unit (rcb>>2)&1
      const int toff = rrow * 64 + ((rcb >> 3) ^ (rrow & 7)) * 8 + ((rcb >> 2) & 1) * 4;
      unsigned short* hd = hbuf + (size_t)((t + 1) & 1) * (Bsz * Hsz) +
                           (size_t)(cg * 8 + rg) * 1024 + toff;
      if (use_l2) {
        // plain write-back store: dirty in the SHARED XCD L2 (coherent for
        // same-L2 readers; eviction goes to L3 which SC0 readers then fill from)
        *reinterpret_cast<unsigned long long*>(hd) = pk;
      } else {
        // device-coherent store: write-through to L3 (the coherence point)
        __hip_atomic_store(reinterpret_cast<unsigned long long*>(hd), pk,
                           __ATOMIC_RELAXED, __HIP_MEMORY_SCOPE_AGENT);
      }
      if (pad_lds[rrow] == t) {
        float4 o;
        o.x = t0; o.y = t1; o.z = t2; o.w = t3;
        *reinterpret_cast<float4*>(&hfinal[(size_t)(b0 + rrow) * Hsz + c0 + rcb]) = o;
      }
    }

    __syncthreads();  // barrier #2: full vmcnt drain -> h committed before post

    if (have_next && tid == 0) {
      // single-writer flag: plain relaxed coherent store, no RMW, no fence
      __hip_atomic_store(flags + cg * 8 + rg, (unsigned)(t + 1),
                         __ATOMIC_RELAXED, __HIP_MEMORY_SCOPE_AGENT);
    }
  }
}

// out[b][o] = hfinal[b][:] . W_fc[o][:] + b_fc[o]; 8 b-tiles x 32 o-tiles
__global__ __launch_bounds__(64)
void fc_kernel(const float* __restrict__ hfinal, const float* __restrict__ W_fc,
               const float* __restrict__ b_fc, float* __restrict__ out) {
  const int lane = threadIdx.x & 63;
  const int m16 = lane & 15;
  const int quad = lane >> 4;
  const int b0 = (blockIdx.x & 7) * 16;
  const int o0 = (blockIdx.x >> 3) * 16;
  floatx4 acc = {0.f, 0.f, 0.f, 0.f};
  const float* ap = hfinal + (size_t)(b0 + m16) * Hsz + quad * 8;
  const float* bp = W_fc + (size_t)(o0 + m16) * Hsz + quad * 8;
#pragma unroll 4
  for (int kc = 0; kc < 64; ++kc) {
    short8 a, b;
#pragma unroll
    for (int j = 0; j < 8; ++j) a[j] = (short)f2bf(ap[kc * 32 + j]);
#pragma unroll
    for (int j = 0; j < 8; ++j) b[j] = (short)f2bf(bp[kc * 32 + j]);
    acc = __builtin_amdgcn_mfma_f32_16x16x32_bf16(a, b, acc, 0, 0, 0);
  }
  const float bias = b_fc[o0 + m16];
#pragma unroll
  for (int i = 0; i < 4; ++i)
    out[(size_t)(b0 + quad * 4 + i) * Osz + o0 + m16] = acc[i] + bias;
}

__global__ void zero_flags(unsigned int* f) { f[blockIdx.x * 256 + threadIdx.x] = 0u; }

extern "C" void kernel_launch(void* const* d_in, const int* in_sizes, int n_in,
                              void* d_out, int out_size, void* d_ws, size_t ws_size,
                              hipStream_t stream) {
  const float* x = (const float*)d_in[0];
  const float* h0 = (const float*)d_in[1];
  const float* W_ih = (const float*)d_in[2];
  const float* b_ih = (const float*)d_in[3];
  const float* W_hh = (const float*)d_in[4];
  const float* b_hh = (const float*)d_in[5];
  const float* W_fc = (const float*)d_in[6];
  const float* b_fc = (const float*)d_in[7];
  float* out = (float*)d_out;

  char* ws = (char*)d_ws;
  unsigned short* hbuf = (unsigned short*)ws;              // 1 MiB (2x 512KB tile slabs)
  float* hfinal = (float*)(ws + (1u << 20));               // 1 MiB
  unsigned int* flags = (unsigned int*)(ws + (2u << 20));  // 1 KiB flags [32cg][8rg]
  unsigned int* xcc_arr = flags + 256;                     // 1 KiB xcc ids
  unsigned int* claimed = flags + 512;                     // 1 KiB claim map
  unsigned int* xcd_cnt = flags + 768;                     // 8 tickets
  unsigned int* done_cnt = flags + 776;                    // 1 rendezvous ctr

  zero_flags<<<4, 256, 0, stream>>>(flags);  // zero flags+xcc+claimed+cnts (1024 dwords)
  rnn_kernel<<<256, 256, 0, stream>>>(x, h0, W_ih, b_ih, W_hh, b_hh, hbuf, hfinal,
                                      flags, xcc_arr, claimed, xcd_cnt, done_cnt);
  fc_kernel<<<256, 64, 0, stream>>>(hfinal, W_fc, b_fc, out);
}

// Round 9
// 2050.585 us; speedup vs baseline: 1.3498x; 1.0248x over previous
//
#include <hip/hip_runtime.h>

// Problem: B=128, T=512, I=512, H=2048, O=512, steps = T-2 = 510.
// Persistent-RNN, R15: PROGRESSIVE in-order DMA issue.
//   R10-R14 falsified: DMA exposure, poll-line contention, barrier
//   rendezvous, post latency, occupancy, XCD placement -- all neutral at
//   ~2070us. Remaining untested chain component: the all-or-nothing poll.
//   The __all ballot waits for the SLOWEST of 8 producers before issuing ANY
//   of the 16 h DMAs, so each step pays max(straggler spread) + full DMA
//   flight serially. Change: poll all 8 flags per iteration (one ballot) and
//   immediately issue the chunk DMAs for the ready PREFIX (strict order
//   0..7). Early chunks' DMA flight overlaps the straggler wait; HCHUNK's
//   per-chunk vmcnt(14-2c) gating stays valid (same issue order).
//   Sync semantics FROZEN from R6/R10: relaxed agent flag store after
//   barrier #2, relaxed agent ballot poll, dual L2/L3 data path.
#define Bsz 128
#define Tsz 512
#define Isz 512
#define Hsz 2048
#define Osz 512
#define STEPS 510

typedef short short8 __attribute__((ext_vector_type(8)));
typedef float floatx4 __attribute__((ext_vector_type(4)));

// fp32 -> bf16 round-to-nearest-even (finite inputs only)
__device__ __forceinline__ unsigned short f2bf(float f) {
  unsigned int u = __builtin_bit_cast(unsigned int, f);
  u += 0x7FFFu + ((u >> 16) & 1u);
  return (unsigned short)(u >> 16);
}

// exact identity tanh(x) = 1 - 2/(e^{2x}+1); exp+rcp ~1ulp, abs err ~1e-7
__device__ __forceinline__ float tanh_fast(float x) {
  const float e = __expf(2.f * x);
  return 1.f - 2.f * __builtin_amdgcn_rcpf(e + 1.f);
}

// async global->LDS, 16B/lane; global src per-lane (ptr + lane*16B), LDS dest
// wave-uniform base. AUX CPol: 0x11 = SC0|SC1 (device-coherent, read L3),
// 0x01 = SC0 (bypass L1 only; read shared XCD L2 -- hits producer-dirty lines)
template <int AUX>
__device__ __forceinline__ void gload_lds16(const void* g, void* l) {
  __builtin_amdgcn_global_load_lds(
      (const __attribute__((address_space(1))) void*)g,
      (__attribute__((address_space(3))) void*)l, 16, 0, AUX);
}

// h-chunk compute: wait for chunk c's two DMAs (issue-order retirement =>
// complete when <= 14-2c VMEM ops outstanding), then 2 LDS vector reads +
// 8 MFMAs. enc = 0x0F70 | (14-2c). Waits are upper bounds: pass trivially
// if fewer ops are outstanding (e.g. retired early or t=0 prefill).
#define HCHUNK(c, enc)                                                                         \
  {                                                                                            \
    __builtin_amdgcn_s_waitcnt(enc);                                                           \
    const int hb = wvoff + (c) * 1024 + m16 * 64;                                              \
    const short8 a0 = *reinterpret_cast<const short8*>(&h_lds[hb + (quad ^ m7) * 8]);          \
    acc[0] = __builtin_amdgcn_mfma_f32_16x16x32_bf16(a0, wf[(c) * 2][0], acc[0], 0, 0, 0);     \
    acc[1] = __builtin_amdgcn_mfma_f32_16x16x32_bf16(a0, wf[(c) * 2][1], acc[1], 0, 0, 0);     \
    acc[2] = __builtin_amdgcn_mfma_f32_16x16x32_bf16(a0, wf[(c) * 2][2], acc[2], 0, 0, 0);     \
    acc[3] = __builtin_amdgcn_mfma_f32_16x16x32_bf16(a0, wf[(c) * 2][3], acc[3], 0, 0, 0);     \
    const short8 a1 = *reinterpret_cast<const short8*>(&h_lds[hb + ((4 + quad) ^ m7) * 8]);    \
    acc[0] = __builtin_amdgcn_mfma_f32_16x16x32_bf16(a1, wf[(c) * 2 + 1][0], acc[0], 0, 0, 0); \
    acc[1] = __builtin_amdgcn_mfma_f32_16x16x32_bf16(a1, wf[(c) * 2 + 1][1], acc[1], 0, 0, 0); \
    acc[2] = __builtin_amdgcn_mfma_f32_16x16x32_bf16(a1, wf[(c) * 2 + 1][2], acc[2], 0, 0, 0); \
    acc[3] = __builtin_amdgcn_mfma_f32_16x16x32_bf16(a1, wf[(c) * 2 + 1][3], acc[3], 0, 0, 0); \
  }

__global__ __launch_bounds__(256, 1)
void rnn_kernel(const float* __restrict__ x, const float* __restrict__ h0v,
                const float* __restrict__ W_ih, const float* __restrict__ b_ih,
                const float* __restrict__ W_hh, const float* __restrict__ b_hh,
                unsigned short* __restrict__ hbuf,  // [2][32 cg][8 rg][1024] swizzled bf16 tiles
                float* __restrict__ hfinal,         // [128][2048] f32
                unsigned int* __restrict__ flags,   // [32 cg][8 rg] step counters
                unsigned int* __restrict__ xcc_arr) // [8 rg][32 cg] XCC id + 1
{
  __shared__ short h_lds[4 * 8192];   // 64 KB: per-wave 8 chunk-tiles [16][64], swizzled
  __shared__ float red_lds[4 * 1024]; // 16 KB: k-split partials
  __shared__ int pad_lds[16];
  __shared__ unsigned int mode_lds;   // 1 = same-XCD L2 exchange legal

  const int tid = threadIdx.x;
  const int lane = tid & 63;
  const int wv = tid >> 6;    // wave 0..3 -> k-quarter
  const int m16 = lane & 15;  // MFMA: A row / B col / C col
  const int quad = lane >> 4;
  const int m7 = m16 & 7;
  const int rg = blockIdx.x & 7;   // row group (bid%8 -> XCD under round-robin)
  const int cg = blockIdx.x >> 3;  // col group 0..31
  const int b0 = rg * 16;
  const int c0 = cg * 64;
  const int kq = wv * 512;   // W_hh k-range for this wave
  const int kqx = wv * 128;  // W_ih k-range
  const int wvoff = wv * 8192;  // this wave's h_lds region (shorts)

  // ---- runtime XCD-colocation check (publish + verify all 32 rg members) ----
  {
    unsigned int xcc;
    asm volatile("s_getreg_b32 %0, hwreg(HW_REG_XCC_ID)" : "=s"(xcc));
    if (tid == 0)
      __hip_atomic_store(&xcc_arr[rg * 32 + cg], xcc + 1u, __ATOMIC_RELAXED,
                         __HIP_MEMORY_SCOPE_AGENT);
    if (wv == 0) {
      const unsigned int* ap = &xcc_arr[rg * 32 + (lane & 31)];
      unsigned int v;
      do {
        v = __hip_atomic_load(ap, __ATOMIC_RELAXED, __HIP_MEMORY_SCOPE_AGENT);
        if (__all((int)(v != 0u))) break;
        __builtin_amdgcn_s_sleep(2);
      } while (true);
      const int same = __all((int)(v == xcc + 1u));
      if (tid == 0) mode_lds = (unsigned int)same;
    }
  }

  // ---- one-time: weight slices -> bf16 B-fragments in registers ----
  // B-frag: lane holds B[k = quad*8 + j][n = lane&15]
  short8 wf[16][4];  // [kchunk within quarter][ntile]
  short8 wih[4][4];
#pragma unroll
  for (int nt = 0; nt < 4; ++nt) {
    const int wrow = c0 + nt * 16 + m16;  // W row = output col j
    const float* base = W_hh + (size_t)wrow * Hsz + kq + quad * 8;
#pragma unroll
    for (int kc = 0; kc < 16; ++kc) {
      short8 v;
#pragma unroll
      for (int j = 0; j < 8; ++j) v[j] = (short)f2bf(base[kc * 32 + j]);
      wf[kc][nt] = v;
    }
    const float* basex = W_ih + (size_t)wrow * Isz + kqx + quad * 8;
#pragma unroll
    for (int kc = 0; kc < 4; ++kc) {
      short8 v;
#pragma unroll
      for (int j = 0; j < 8; ++j) v[j] = (short)f2bf(basex[kc * 32 + j]);
      wih[kc][nt] = v;
    }
  }

  // reduce-phase assignment: thread handles (row=tid>>4, 4 cols at 4*(tid&15))
  const int rrow = tid >> 4;
  const int rcb = (tid & 15) * 4;
  float bias[4];
#pragma unroll
  for (int i = 0; i < 4; ++i) bias[i] = b_ih[c0 + rcb + i] + b_hh[c0 + rcb + i];

  if (tid < 16)
    pad_lds[tid] = (int)x[(size_t)(b0 + tid) * (Tsz * Isz) + (size_t)(Tsz - 1) * Isz];

  // h_0 = h0 broadcast into this wave's 8 tiles (swizzled layout)
  for (int i = lane; i < 1024; i += 64) {  // i = 16B-unit index in wave region
    const int c = i >> 7;          // tile 0..7
    const int r = (i >> 3) & 15;   // row 0..15
    const int u = i & 7;           // unit 0..7
    const int k = kq + c * 64 + u * 8;
    short8 v;
#pragma unroll
    for (int j = 0; j < 8; ++j) v[j] = (short)f2bf(h0v[k + j]);
    *reinterpret_cast<short8*>(&h_lds[wvoff + c * 1024 + r * 64 + (u ^ (r & 7)) * 8]) = v;
  }

  __syncthreads();  // mode_lds + pad_lds visible to all waves
  const bool use_l2 = (mode_lds != 0u);

  // this wave's poll address: lane L watches producer cg' = wv*8 + (L&7).
  // Ballot bit c (lane c's vote, c<8) == producer c ready.
  const unsigned int* fp = flags + (size_t)(wv * 8 + (lane & 7)) * 8 + rg;

  for (int t = 0; t < STEPS; ++t) {
    const bool have_next = (t + 1) < STEPS;

    // x for this step: direct global->VGPR (drained by the first poll's wait)
    const float* xp = x + (size_t)(b0 + m16) * (Tsz * Isz) + (size_t)t * Isz + kqx + quad * 8;
    float4 xv[8];
#pragma unroll
    for (int kcc = 0; kcc < 4; ++kcc) {
      xv[2 * kcc] = *reinterpret_cast<const float4*>(xp + kcc * 32);
      xv[2 * kcc + 1] = *reinterpret_cast<const float4*>(xp + kcc * 32 + 4);
    }

    if (t > 0) {
      // PROGRESSIVE in-order issue: one ballot per iteration; issue the DMA
      // pair for every chunk in the ready PREFIX (order 0..7 preserved for
      // vmcnt gating). Early chunks' flight overlaps the straggler wait.
      const unsigned short* hsrcp = hbuf + (size_t)(t & 1) * (Bsz * Hsz);
      int issued = 0;
      if (use_l2) {
        while (issued < 8) {
          const unsigned int v = __hip_atomic_load(fp, __ATOMIC_RELAXED,
                                                   __HIP_MEMORY_SCOPE_AGENT);
          const unsigned long long rdy = __ballot((int)(v >= (unsigned)t));
          bool prog = false;
          while (issued < 8 && ((rdy >> issued) & 1ull)) {
            const int c = issued;
            const unsigned short* src = hsrcp + (size_t)((wv * 8 + c) * 8 + rg) * 1024;
            gload_lds16<0x01>(src + lane * 8, &h_lds[wvoff + c * 1024]);
            gload_lds16<0x01>(src + 512 + lane * 8, &h_lds[wvoff + c * 1024 + 512]);
            ++issued; prog = true;
          }
          if (issued < 8 && !prog) __builtin_amdgcn_s_sleep(1);
        }
      } else {
        while (issued < 8) {
          const unsigned int v = __hip_atomic_load(fp, __ATOMIC_RELAXED,
                                                   __HIP_MEMORY_SCOPE_AGENT);
          const unsigned long long rdy = __ballot((int)(v >= (unsigned)t));
          bool prog = false;
          while (issued < 8 && ((rdy >> issued) & 1ull)) {
            const int c = issued;
            const unsigned short* src = hsrcp + (size_t)((wv * 8 + c) * 8 + rg) * 1024;
            gload_lds16<0x11>(src + lane * 8, &h_lds[wvoff + c * 1024]);
            gload_lds16<0x11>(src + 512 + lane * 8, &h_lds[wvoff + c * 1024 + 512]);
            ++issued; prog = true;
          }
          if (issued < 8 && !prog) __builtin_amdgcn_s_sleep(1);
        }
      }
    }

    // convert x to A-frags (xv complete: drained by the first poll's wait)
    short8 xa[4];
#pragma unroll
    for (int kcc = 0; kcc < 4; ++kcc) {
      short8 a;
      a[0] = (short)f2bf(xv[2 * kcc].x);
      a[1] = (short)f2bf(xv[2 * kcc].y);
      a[2] = (short)f2bf(xv[2 * kcc].z);
      a[3] = (short)f2bf(xv[2 * kcc].w);
      a[4] = (short)f2bf(xv[2 * kcc + 1].x);
      a[5] = (short)f2bf(xv[2 * kcc + 1].y);
      a[6] = (short)f2bf(xv[2 * kcc + 1].z);
      a[7] = (short)f2bf(xv[2 * kcc + 1].w);
      xa[kcc] = a;
    }

    floatx4 acc[4];
#pragma unroll
    for (int nt = 0; nt < 4; ++nt) {
      floatx4 zero = {0.f, 0.f, 0.f, 0.f};
      acc[nt] = zero;
    }
    // x-projection MFMAs (overlap remaining DMA flight)
#pragma unroll
    for (int kcc = 0; kcc < 4; ++kcc)
#pragma unroll
      for (int nt = 0; nt < 4; ++nt)
        acc[nt] = __builtin_amdgcn_mfma_f32_16x16x32_bf16(xa[kcc], wih[kcc][nt], acc[nt], 0, 0, 0);

    // per-chunk gated h-MFMAs: chunk c complete when <=14-2c VMEM outstanding
    // (waits pass trivially when DMAs already retired, or at t=0).
    HCHUNK(0, 0x0F7E)
    HCHUNK(1, 0x0F7C)
    HCHUNK(2, 0x0F7A)
    HCHUNK(3, 0x0F78)
    HCHUNK(4, 0x0F76)
    HCHUNK(5, 0x0F74)
    HCHUNK(6, 0x0F72)
    HCHUNK(7, 0x0F70)

    // partials -> LDS (C layout: row = quad*4+reg, col = nt*16 + lane&15)
#pragma unroll
    for (int nt = 0; nt < 4; ++nt)
#pragma unroll
      for (int i = 0; i < 4; ++i)
        red_lds[wv * 1024 + (quad * 4 + i) * 64 + nt * 16 + m16] = acc[nt][i];

    __syncthreads();  // barrier #1: partials visible to reduce threads

    // ---- reduce 4 k-partials + bias, tanh, store h_{t+1} tile, capture pad ----
    {
      float4 z = {0.f, 0.f, 0.f, 0.f};
#pragma unroll
      for (int ww = 0; ww < 4; ++ww) {
        const float4 p =
            *reinterpret_cast<const float4*>(&red_lds[ww * 1024 + rrow * 64 + rcb]);
        z.x += p.x; z.y += p.y; z.z += p.z; z.w += p.w;
      }
      const float t0 = tanh_fast(z.x + bias[0]);
      const float t1 = tanh_fast(z.y + bias[1]);
      const float t2 = tanh_fast(z.z + bias[2]);
      const float t3 = tanh_fast(z.w + bias[3]);
      unsigned long long pk = (unsigned long long)f2bf(t0) |
                              ((unsigned long long)f2bf(t1) << 16) |
                              ((unsigned long long)f2bf(t2) << 32) |
                              ((unsigned long long)f2bf(t3) << 48);
      // swizzled tile store: unit (rcb/8) ^ (row&7), half-unit (rcb>>2)&1
      const int toff = rrow * 64 + ((rcb >> 3) ^ (rrow & 7)) * 8 + ((rcb >> 2) & 1) * 4;
      unsigned short* hd = hbuf + (size_t)((t + 1) & 1) * (Bsz * Hsz) +
                           (size_t)(cg * 8 + rg) * 1024 + toff;
      if (use_l2) {
        // plain write-back store: dirty in the SHARED XCD L2 (coherent for
        // same-L2 readers; eviction goes to L3 which SC0 readers then fill from)
        *reinterpret_cast<unsigned long long*>(hd) = pk;
      } else {
        // device-coherent store: write-through to L3 (the coherence point)
        __hip_atomic_store(reinterpret_cast<unsigned long long*>(hd), pk,
                           __ATOMIC_RELAXED, __HIP_MEMORY_SCOPE_AGENT);
      }
      if (pad_lds[rrow] == t) {
        float4 o;
        o.x = t0; o.y = t1; o.z = t2; o.w = t3;
        *reinterpret_cast<float4*>(&hfinal[(size_t)(b0 + rrow) * Hsz + c0 + rcb]) = o;
      }
    }

    __syncthreads();  // barrier #2: full vmcnt drain -> h committed before post

    if (have_next && tid == 0) {
      // single-writer flag: plain relaxed coherent store, no RMW, no fence
      __hip_atomic_store(flags + cg * 8 + rg, (unsigned)(t + 1),
                         __ATOMIC_RELAXED, __HIP_MEMORY_SCOPE_AGENT);
    }
  }
}

// out[b][o] = hfinal[b][:] . W_fc[o][:] + b_fc[o]; 8 b-tiles x 32 o-tiles
__global__ __launch_bounds__(64)
void fc_kernel(const float* __restrict__ hfinal, const float* __restrict__ W_fc,
               const float* __restrict__ b_fc, float* __restrict__ out) {
  const int lane = threadIdx.x & 63;
  const int m16 = lane & 15;
  const int quad = lane >> 4;
  const int b0 = (blockIdx.x & 7) * 16;
  const int o0 = (blockIdx.x >> 3) * 16;
  floatx4 acc = {0.f, 0.f, 0.f, 0.f};
  const float* ap = hfinal + (size_t)(b0 + m16) * Hsz + quad * 8;
  const float* bp = W_fc + (size_t)(o0 + m16) * Hsz + quad * 8;
#pragma unroll 4
  for (int kc = 0; kc < 64; ++kc) {
    short8 a, b;
#pragma unroll
    for (int j = 0; j < 8; ++j) a[j] = (short)f2bf(ap[kc * 32 + j]);
#pragma unroll
    for (int j = 0; j < 8; ++j) b[j] = (short)f2bf(bp[kc * 32 + j]);
    acc = __builtin_amdgcn_mfma_f32_16x16x32_bf16(a, b, acc, 0, 0, 0);
  }
  const float bias = b_fc[o0 + m16];
#pragma unroll
  for (int i = 0; i < 4; ++i)
    out[(size_t)(b0 + quad * 4 + i) * Osz + o0 + m16] = acc[i] + bias;
}

__global__ void zero_flags(unsigned int* f) { f[blockIdx.x * 256 + threadIdx.x] = 0u; }

extern "C" void kernel_launch(void* const* d_in, const int* in_sizes, int n_in,
                              void* d_out, int out_size, void* d_ws, size_t ws_size,
                              hipStream_t stream) {
  const float* x = (const float*)d_in[0];
  const float* h0 = (const float*)d_in[1];
  const float* W_ih = (const float*)d_in[2];
  const float* b_ih = (const float*)d_in[3];
  const float* W_hh = (const float*)d_in[4];
  const float* b_hh = (const float*)d_in[5];
  const float* W_fc = (const float*)d_in[6];
  const float* b_fc = (const float*)d_in[7];
  float* out = (float*)d_out;

  char* ws = (char*)d_ws;
  unsigned short* hbuf = (unsigned short*)ws;              // 1 MiB (2x 512KB tile slabs)
  float* hfinal = (float*)(ws + (1u << 20));               // 1 MiB
  unsigned int* flags = (unsigned int*)(ws + (2u << 20));  // 1 KiB flags
  unsigned int* xcc_arr = flags + 256;                     // 1 KiB xcc ids

  zero_flags<<<2, 256, 0, stream>>>(flags);  // zero flags + xcc_arr
  rnn_kernel<<<256, 256, 0, stream>>>(x, h0, W_ih, b_ih, W_hh, b_hh, hbuf, hfinal,
                                      flags, xcc_arr);
  fc_kernel<<<256, 64, 0, stream>>>(hfinal, W_fc, b_fc, out);
}